// Round 1
// baseline (521.834 us; speedup 1.0000x reference)
//
#include <hip/hip_runtime.h>
#include <math.h>

namespace {
constexpr int   N_T = 100;   // time steps
constexpr int   M1  = 12;    // basis per dim
constexpr float LB  = 4.5f;  // HSGP half-domain L = c * S = 1.5 * 3.0
constexpr int   DC  = 3;     // metric components
}

// ---------------------------------------------------------------------------
// Setup: fold spectral-density sqrt weights + norm into beta.
// Bs[(a*12+b)*3 + d] = beta[d, a*12+b] * sqrt(S(a,b)) * L^{-1}
// ---------------------------------------------------------------------------
__global__ void setup_B_kernel(const float* __restrict__ beta,
                               const float* __restrict__ ls,
                               const float* __restrict__ alpha,
                               float* __restrict__ Bs) {
    int idx = blockIdx.x * blockDim.x + threadIdx.x;
    if (idx >= M1 * M1 * DC) return;
    int d  = idx % DC;
    int ab = idx / DC;
    int bb = ab % M1;
    int a  = ab / M1;
    float w0 = (float)M_PI * (float)(a + 1)  / (2.0f * LB);
    float w1 = (float)M_PI * (float)(bb + 1) / (2.0f * LB);
    float l0 = ls[0], l1 = ls[1], al = alpha[0];
    float S = al * al * (2.0f * (float)M_PI) * l0 * l1 *
              expf(-0.5f * (l0 * l0 * w0 * w0 + l1 * l1 * w1 * w1));
    float sq = sqrtf(S);
    float nrm = 1.0f / LB;               // LB^{-0.5*n}, n=2
    Bs[idx] = beta[d * (M1 * M1) + ab] * sq * nrm;
}

// ---------------------------------------------------------------------------
// Main: one thread integrates one batch element for all 99 steps.
// ---------------------------------------------------------------------------
__global__ __launch_bounds__(64, 1)
void geo_kernel(const float* __restrict__ xg, const float* __restrict__ vg,
                const float* __restrict__ Bs, float* __restrict__ out, int B)
{
    int b = blockIdx.x * 64 + threadIdx.x;
    if (b >= B) return;

    const float W = (float)M_PI / (2.0f * LB);   // base frequency
    float x0 = xg[2 * b + 0], x1 = xg[2 * b + 1];
    float v0 = vg[2 * b + 0], v1 = vg[2 * b + 1];

    float2* out2 = reinterpret_cast<float2*>(out);
    // t = 0: y0
    out2[(size_t)0 * B + b] = make_float2(x0, x1);
    out2[(size_t)1 * B + b] = make_float2(v0, v1);

    // Adams history (newest first), zeros initially; AB coeffs handle startup.
    float hvx[4] = {0.f, 0.f, 0.f, 0.f};
    float hvy[4] = {0.f, 0.f, 0.f, 0.f};
    float hax[4] = {0.f, 0.f, 0.f, 0.f};
    float hay[4] = {0.f, 0.f, 0.f, 0.f};
    const float h = (float)(1.0 / 99.0);

    #pragma unroll 1
    for (int t = 0; t < N_T - 1; ++t) {
        // ---- per-dim sin / (w*cos) tables via angle-addition recurrence ----
        float s0[M1], wc0[M1], s1[M1], wc1[M1];
        {
            float th = W * (x0 + LB);
            float bs, bc;
            sincosf(th, &bs, &bc);
            float sk = bs, ck = bc;
            s0[0] = sk; wc0[0] = W * ck;
            #pragma unroll
            for (int k = 1; k < M1; ++k) {
                float sn = fmaf(sk, bc,  ck * bs);
                float cn = fmaf(ck, bc, -(sk * bs));
                sk = sn; ck = cn;
                s0[k] = sk; wc0[k] = (W * (float)(k + 1)) * ck;
            }
        }
        {
            float th = W * (x1 + LB);
            float bs, bc;
            sincosf(th, &bs, &bc);
            float sk = bs, ck = bc;
            s1[0] = sk; wc1[0] = W * ck;
            #pragma unroll
            for (int k = 1; k < M1; ++k) {
                float sn = fmaf(sk, bc,  ck * bs);
                float cn = fmaf(ck, bc, -(sk * bs));
                sk = sn; ck = cn;
                s1[k] = sk; wc1[k] = (W * (float)(k + 1)) * ck;
            }
        }

        // ---- f[d], df[d][0] (dA), df[d][1] (dB) via separable contraction ----
        float f0 = 0.f, f1 = 0.f, f2 = 0.f;
        float dA0 = 0.f, dA1 = 0.f, dA2 = 0.f;   // d/dx0
        float dB0 = 0.f, dB1 = 0.f, dB2 = 0.f;   // d/dx1
        #pragma unroll
        for (int a = 0; a < M1; ++a) {
            float iS0 = 0.f, iS1 = 0.f, iS2 = 0.f;   // sum_b Bs * s1[b]
            float iC0 = 0.f, iC1 = 0.f, iC2 = 0.f;   // sum_b Bs * w1[b]*c1[b]
            #pragma unroll
            for (int j = 0; j < M1; ++j) {
                float B0 = Bs[(a * M1 + j) * 3 + 0];
                float B1 = Bs[(a * M1 + j) * 3 + 1];
                float B2 = Bs[(a * M1 + j) * 3 + 2];
                float sB = s1[j], cB = wc1[j];
                iS0 = fmaf(B0, sB, iS0);
                iS1 = fmaf(B1, sB, iS1);
                iS2 = fmaf(B2, sB, iS2);
                iC0 = fmaf(B0, cB, iC0);
                iC1 = fmaf(B1, cB, iC1);
                iC2 = fmaf(B2, cB, iC2);
            }
            float sA = s0[a], cA = wc0[a];
            f0  = fmaf(sA, iS0, f0);   f1  = fmaf(sA, iS1, f1);   f2  = fmaf(sA, iS2, f2);
            dA0 = fmaf(cA, iS0, dA0);  dA1 = fmaf(cA, iS1, dA1);  dA2 = fmaf(cA, iS2, dA2);
            dB0 = fmaf(sA, iC0, dB0);  dB1 = fmaf(sA, iC1, dB1);  dB2 = fmaf(sA, iC2, dB2);
        }

        // ---- 2x2 Christoffel acceleration ----
        // G = [[f0+1, f1],[f1, f2+1]];  D[d][i]: i=0 -> dA_d, i=1 -> dB_d
        float G00 = f0 + 1.0f, G01 = f1, G11 = f2 + 1.0f;
        float det = fmaf(G00, G11, -(G01 * G01));
        float rdet = 1.0f / det;
        float vv00 = v0 * v0, vv01 = v0 * v1, vv11 = v1 * v1;
        // q_l = 2*A_l - B_l  (A_l = d_i g_lj v^i v^j, B_l = d_l g_ij v^i v^j)
        float q0 = dA0 * vv00 + 2.0f * dB0 * vv01 + fmaf(2.0f, dB1, -dA2) * vv11;
        float q1 = fmaf(2.0f, dA1, -dB0) * vv00 + 2.0f * dA2 * vv01 + dB2 * vv11;
        float a0 = -0.5f * rdet * (G11 * q0 - G01 * q1);
        float a1 = -0.5f * rdet * (G00 * q1 - G01 * q0);

        // ---- Adams-Bashforth update (explicit, order<=4 startup) ----
        #pragma unroll
        for (int q = 3; q > 0; --q) {
            hvx[q] = hvx[q - 1]; hvy[q] = hvy[q - 1];
            hax[q] = hax[q - 1]; hay[q] = hay[q - 1];
        }
        hvx[0] = v0; hvy[0] = v1; hax[0] = a0; hay[0] = a1;

        float c0, c1, c2, c3;
        if (t >= 3)      { c0 = 55.0f/24.0f; c1 = -59.0f/24.0f; c2 = 37.0f/24.0f; c3 = -9.0f/24.0f; }
        else if (t == 2) { c0 = 23.0f/12.0f; c1 = -16.0f/12.0f; c2 = 5.0f/12.0f;  c3 = 0.0f; }
        else if (t == 1) { c0 = 1.5f; c1 = -0.5f; c2 = 0.0f; c3 = 0.0f; }
        else             { c0 = 1.0f; c1 = 0.0f;  c2 = 0.0f; c3 = 0.0f; }

        x0 += h * (c0 * hvx[0] + c1 * hvx[1] + c2 * hvx[2] + c3 * hvx[3]);
        x1 += h * (c0 * hvy[0] + c1 * hvy[1] + c2 * hvy[2] + c3 * hvy[3]);
        v0 += h * (c0 * hax[0] + c1 * hax[1] + c2 * hax[2] + c3 * hax[3]);
        v1 += h * (c0 * hay[0] + c1 * hay[1] + c2 * hay[2] + c3 * hay[3]);

        out2[(size_t)((t + 1) * 2 + 0) * B + b] = make_float2(x0, x1);
        out2[(size_t)((t + 1) * 2 + 1) * B + b] = make_float2(v0, v1);
    }
}

// ---------------------------------------------------------------------------
extern "C" void kernel_launch(void* const* d_in, const int* in_sizes, int n_in,
                              void* d_out, int out_size, void* d_ws, size_t ws_size,
                              hipStream_t stream) {
    const float* x0    = (const float*)d_in[0];
    const float* v0    = (const float*)d_in[1];
    const float* beta  = (const float*)d_in[2];
    const float* ls    = (const float*)d_in[3];
    const float* alpha = (const float*)d_in[4];
    float* out = (float*)d_out;
    float* Bs  = (float*)d_ws;   // 432 floats

    int B = in_sizes[0] / 2;     // 50000

    hipLaunchKernelGGL(setup_B_kernel, dim3(7), dim3(64), 0, stream,
                       beta, ls, alpha, Bs);

    int grid = (B + 63) / 64;
    hipLaunchKernelGGL(geo_kernel, dim3(grid), dim3(64), 0, stream,
                       x0, v0, Bs, out, B);
}

// Round 2
// 231.979 us; speedup vs baseline: 2.2495x; 2.2495x over previous
//
#include <hip/hip_runtime.h>
#include <math.h>

typedef float v2f __attribute__((ext_vector_type(2)));

namespace {
constexpr int   N_T = 100;   // time steps
constexpr int   M1  = 12;    // basis per dim
constexpr float LB  = 4.5f;  // HSGP half-domain L = c * S = 1.5 * 3.0
}

// ---------------------------------------------------------------------------
// Setup: fold spectral-density sqrt weights + norm into beta.
// Layout for the main kernel: Bs[(a*3 + d)*12 + j] (j contiguous, paired)
// ---------------------------------------------------------------------------
__global__ void setup_B_kernel(const float* __restrict__ beta,
                               const float* __restrict__ ls,
                               const float* __restrict__ alpha,
                               float* __restrict__ Bs) {
    int idx = blockIdx.x * blockDim.x + threadIdx.x;
    if (idx >= M1 * M1 * 3) return;
    int j = idx % M1;
    int d = (idx / M1) % 3;
    int a = idx / (M1 * 3);
    float w0 = (float)M_PI * (float)(a + 1) / (2.0f * LB);
    float w1 = (float)M_PI * (float)(j + 1) / (2.0f * LB);
    float l0 = ls[0], l1 = ls[1], al = alpha[0];
    float S = al * al * (2.0f * (float)M_PI) * l0 * l1 *
              expf(-0.5f * (l0 * l0 * w0 * w0 + l1 * l1 * w1 * w1));
    Bs[idx] = beta[d * (M1 * M1) + a * M1 + j] * sqrtf(S) * (1.0f / LB);
}

// ---------------------------------------------------------------------------
// quad (4-lane) butterfly sum via DPP quad_perm — pure VALU, no LDS
// ---------------------------------------------------------------------------
__device__ __forceinline__ float quad_sum(float v) {
    int t = __builtin_amdgcn_mov_dpp(__float_as_int(v), 0xB1, 0xF, 0xF, true); // [1,0,3,2]
    v += __int_as_float(t);
    t = __builtin_amdgcn_mov_dpp(__float_as_int(v), 0x4E, 0xF, 0xF, true);     // [2,3,0,1]
    v += __int_as_float(t);
    return v;
}

// ---------------------------------------------------------------------------
// Main: 4 lanes cooperate on one batch element. Lane q owns a in {3q..3q+2}.
// All Bs values live in VGPRs; K-loop has no memory reads.
// ---------------------------------------------------------------------------
__global__ __launch_bounds__(64, 2)
void geo_kernel(const float* __restrict__ xg, const float* __restrict__ vg,
                const float* __restrict__ Bs, float* __restrict__ out, int B)
{
    int tid = blockIdx.x * 64 + threadIdx.x;
    int e = tid >> 2;            // element index
    int q = tid & 3;             // quad sub-lane
    if (e >= B) return;

    const float W = (float)M_PI / (2.0f * LB);

    // per-lane dim0 multipliers: a+1 for a = 3q+r
    float m0 = (float)(3 * q + 1);
    float m1 = (float)(3 * q + 2);
    float m2 = (float)(3 * q + 3);
    float Wm0 = W * m0, Wm1 = W * m1, Wm2 = W * m2;

    // ---- preload this lane's 3 a-rows of Bs into VGPRs (packed over j) ----
    v2f pB[3][3][6];
    {
        const v2f* pBg = reinterpret_cast<const v2f*>(Bs) + (size_t)(3 * q) * 18;
        #pragma unroll
        for (int r = 0; r < 3; ++r)
            #pragma unroll
            for (int d = 0; d < 3; ++d)
                #pragma unroll
                for (int jp = 0; jp < 6; ++jp)
                    pB[r][d][jp] = pBg[(r * 3 + d) * 6 + jp];
    }

    // packed wc constants (W*(2k+1), W*(2k+2)) — loop-invariant
    v2f pkW[6];
    #pragma unroll
    for (int k = 0; k < 6; ++k)
        pkW[k] = (v2f){W * (float)(2 * k + 1), W * (float)(2 * k + 2)};

    float x0 = xg[2 * e + 0], x1 = xg[2 * e + 1];
    float v0 = vg[2 * e + 0], v1 = vg[2 * e + 1];

    float2* out2 = reinterpret_cast<float2*>(out);
    if (q == 0) out2[(size_t)0 * B + e] = make_float2(x0, x1);
    if (q == 1) out2[(size_t)1 * B + e] = make_float2(v0, v1);

    float hvx[4] = {0.f, 0.f, 0.f, 0.f};
    float hvy[4] = {0.f, 0.f, 0.f, 0.f};
    float hax[4] = {0.f, 0.f, 0.f, 0.f};
    float hay[4] = {0.f, 0.f, 0.f, 0.f};
    const float h = (float)(1.0 / 99.0);

    #pragma unroll 1
    for (int t = 0; t < N_T - 1; ++t) {
        // ---- dim1 packed tables via double-angle recurrence ----
        // ps[k] = (sin((2k+1)th), sin((2k+2)th)); pc[k] = cos analog
        float th1 = W * (x1 + LB);
        float s1 = __sinf(th1), c1 = __cosf(th1);
        float s2 = 2.0f * s1 * c1;
        float c2 = fmaf(-2.0f * s1, s1, 1.0f);
        v2f ps[6], pc[6], pwc[6];
        ps[0] = (v2f){s1, s2};
        pc[0] = (v2f){c1, c2};
        v2f c2s = (v2f){c2, c2}, s2s = (v2f){s2, s2};
        #pragma unroll
        for (int k = 1; k < 6; ++k) {
            ps[k] = __builtin_elementwise_fma(ps[k - 1], c2s, pc[k - 1] * s2s);
            pc[k] = __builtin_elementwise_fma(pc[k - 1], c2s, -(ps[k - 1] * s2s));
        }
        #pragma unroll
        for (int k = 0; k < 6; ++k) pwc[k] = pkW[k] * pc[k];

        // ---- dim0: direct HW sincos at this lane's 3 multiples ----
        float th0 = W * (x0 + LB);
        float s0v[3], wc0v[3];
        {
            float a0 = m0 * th0, a1 = m1 * th0, a2 = m2 * th0;
            s0v[0] = __sinf(a0); wc0v[0] = Wm0 * __cosf(a0);
            s0v[1] = __sinf(a1); wc0v[1] = Wm1 * __cosf(a1);
            s0v[2] = __sinf(a2); wc0v[2] = Wm2 * __cosf(a2);
        }

        // ---- contraction over this lane's 3 a-rows (packed over j) ----
        float f0 = 0.f, f1 = 0.f, f2 = 0.f;
        float dA0 = 0.f, dA1 = 0.f, dA2 = 0.f;
        float dB0 = 0.f, dB1 = 0.f, dB2 = 0.f;
        #pragma unroll
        for (int r = 0; r < 3; ++r) {
            v2f aS0 = (v2f){0.f, 0.f}, aS1 = aS0, aS2 = aS0;
            v2f aC0 = aS0, aC1 = aS0, aC2 = aS0;
            #pragma unroll
            for (int jp = 0; jp < 6; ++jp) {
                v2f s = ps[jp], c = pwc[jp];
                aS0 = __builtin_elementwise_fma(pB[r][0][jp], s, aS0);
                aC0 = __builtin_elementwise_fma(pB[r][0][jp], c, aC0);
                aS1 = __builtin_elementwise_fma(pB[r][1][jp], s, aS1);
                aC1 = __builtin_elementwise_fma(pB[r][1][jp], c, aC1);
                aS2 = __builtin_elementwise_fma(pB[r][2][jp], s, aS2);
                aC2 = __builtin_elementwise_fma(pB[r][2][jp], c, aC2);
            }
            float iS0 = aS0.x + aS0.y, iC0 = aC0.x + aC0.y;
            float iS1 = aS1.x + aS1.y, iC1 = aC1.x + aC1.y;
            float iS2 = aS2.x + aS2.y, iC2 = aC2.x + aC2.y;
            float sA = s0v[r], cA = wc0v[r];
            f0  = fmaf(sA, iS0, f0);   f1  = fmaf(sA, iS1, f1);   f2  = fmaf(sA, iS2, f2);
            dA0 = fmaf(cA, iS0, dA0);  dA1 = fmaf(cA, iS1, dA1);  dA2 = fmaf(cA, iS2, dA2);
            dB0 = fmaf(sA, iC0, dB0);  dB1 = fmaf(sA, iC1, dB1);  dB2 = fmaf(sA, iC2, dB2);
        }

        // ---- combine the 4 lanes' partials (all lanes end with full sums) ----
        f0  = quad_sum(f0);   f1  = quad_sum(f1);   f2  = quad_sum(f2);
        dA0 = quad_sum(dA0);  dA1 = quad_sum(dA1);  dA2 = quad_sum(dA2);
        dB0 = quad_sum(dB0);  dB1 = quad_sum(dB1);  dB2 = quad_sum(dB2);

        // ---- 2x2 Christoffel acceleration (redundant on all 4 lanes) ----
        float G00 = f0 + 1.0f, G01 = f1, G11 = f2 + 1.0f;
        float det = fmaf(G00, G11, -(G01 * G01));
        float rdet = 1.0f / det;
        float vv00 = v0 * v0, vv01 = v0 * v1, vv11 = v1 * v1;
        float q0 = dA0 * vv00 + 2.0f * dB0 * vv01 + fmaf(2.0f, dB1, -dA2) * vv11;
        float q1 = fmaf(2.0f, dA1, -dB0) * vv00 + 2.0f * dA2 * vv01 + dB2 * vv11;
        float a0 = -0.5f * rdet * (G11 * q0 - G01 * q1);
        float a1 = -0.5f * rdet * (G00 * q1 - G01 * q0);

        // ---- Adams-Bashforth update ----
        #pragma unroll
        for (int p = 3; p > 0; --p) {
            hvx[p] = hvx[p - 1]; hvy[p] = hvy[p - 1];
            hax[p] = hax[p - 1]; hay[p] = hay[p - 1];
        }
        hvx[0] = v0; hvy[0] = v1; hax[0] = a0; hay[0] = a1;

        float c0, c1c, c2c, c3;
        if (t >= 3)      { c0 = 55.0f/24.0f; c1c = -59.0f/24.0f; c2c = 37.0f/24.0f; c3 = -9.0f/24.0f; }
        else if (t == 2) { c0 = 23.0f/12.0f; c1c = -16.0f/12.0f; c2c = 5.0f/12.0f;  c3 = 0.0f; }
        else if (t == 1) { c0 = 1.5f; c1c = -0.5f; c2c = 0.0f; c3 = 0.0f; }
        else             { c0 = 1.0f; c1c = 0.0f;  c2c = 0.0f; c3 = 0.0f; }

        x0 += h * (c0 * hvx[0] + c1c * hvx[1] + c2c * hvx[2] + c3 * hvx[3]);
        x1 += h * (c0 * hvy[0] + c1c * hvy[1] + c2c * hvy[2] + c3 * hvy[3]);
        v0 += h * (c0 * hax[0] + c1c * hax[1] + c2c * hax[2] + c3 * hax[3]);
        v1 += h * (c0 * hay[0] + c1c * hay[1] + c2c * hay[2] + c3 * hay[3]);

        if (q == 0) out2[(size_t)((t + 1) * 2 + 0) * B + e] = make_float2(x0, x1);
        if (q == 1) out2[(size_t)((t + 1) * 2 + 1) * B + e] = make_float2(v0, v1);
    }
}

// ---------------------------------------------------------------------------
extern "C" void kernel_launch(void* const* d_in, const int* in_sizes, int n_in,
                              void* d_out, int out_size, void* d_ws, size_t ws_size,
                              hipStream_t stream) {
    const float* x0    = (const float*)d_in[0];
    const float* v0    = (const float*)d_in[1];
    const float* beta  = (const float*)d_in[2];
    const float* ls    = (const float*)d_in[3];
    const float* alpha = (const float*)d_in[4];
    float* out = (float*)d_out;
    float* Bs  = (float*)d_ws;   // 432 floats, layout [a][d][j]

    int B = in_sizes[0] / 2;     // 50000

    hipLaunchKernelGGL(setup_B_kernel, dim3(7), dim3(64), 0, stream,
                       beta, ls, alpha, Bs);

    long threads = 4L * B;
    int grid = (int)((threads + 63) / 64);
    hipLaunchKernelGGL(geo_kernel, dim3(grid), dim3(64), 0, stream,
                       x0, v0, Bs, out, B);
}